// Round 12
// baseline (89.959 us; speedup 1.0000x reference)
//
#include <hip/hip_runtime.h>

constexpr int BB = 16;        // batch
constexpr int HH = 512;
constexpr int WW = 512;
constexpr int HW = HH * WW;   // 262144 = 2^18
constexpr int NP1 = BB * HW;  // one single-channel plane (elements)

using half_t = _Float16;
using half2v = __attribute__((ext_vector_type(2))) _Float16;
using half8v = __attribute__((ext_vector_type(8))) _Float16;

// 11-tap Gaussian, theta=1, normalized (== normal pdf values to ~1e-8 rel).
__device__ constexpr float GK[11] = {
    1.4867195147342977e-06f,
    1.3383022576488537e-04f,
    4.4318484119380075e-03f,
    5.3990966513188063e-02f,
    2.4197072451914337e-01f,
    3.9894228040143270e-01f,
    2.4197072451914337e-01f,
    5.3990966513188063e-02f,
    4.4318484119380075e-03f,
    1.3383022576488537e-04f,
    1.4867195147342977e-06f,
};
// prefix sums of the smallest taps: PFX[k] = GK[0]+..+GK[k-1]
__device__ constexpr float PFX[6] = {
    0.0f,
    1.4867195147342977e-06f,
    1.3531694527962e-04f,
    4.5671653572176e-03f,
    5.8558131870406e-02f,
    3.0052885638955e-01f,
};

// blur(ones) separable factor with zero padding
__device__ __forceinline__ float edgeS(int i) {
    float s = 1.f;
    if (i < 5)   s -= PFX[5 - i];
    if (i > 506) s -= PFX[i - 506];
    return s;
}

__device__ __forceinline__ float sig1(float d) {
    d = fminf(fmaxf(d, -30.f), 30.f);
    float e = __expf(d);
    return e * __builtin_amdgcn_rcpf(1.f + e);
}

// ---------------------------------------------------------------------------
// Kernel 1: 3x3 conv, C_in=3 -> C_out=2, SAME zero-pad (round-11 proven).
// 2 output rows x 8 px per thread; fp16 u0/du planes out.
// ---------------------------------------------------------------------------
__global__ __launch_bounds__(256) void conv3x3_du(
    const float* __restrict__ x, const float* __restrict__ w,
    const float* __restrict__ bias, half_t* __restrict__ u0p,
    half_t* __restrict__ dup)
{
    int bid = blockIdx.x;
    int sb  = (bid & 7) * 128 + (bid >> 3);     // grid 1024, bijective
    int t   = sb * 256 + threadIdx.x;
    int b   = t >> 14;                          // 16384 threads / image
    int rem = t & 16383;
    int y0  = (rem >> 6) << 1;                  // row pair 0,2,..,510
    int xs  = (rem & 63) << 3;                  // 8-px strip

    float W[54];
#pragma unroll
    for (int i = 0; i < 13; ++i)
        *(float4*)&W[4 * i] = *(const float4*)(w + 4 * i);
    W[52] = w[52];
    W[53] = w[53];
    float b0 = bias[0], b1 = bias[1];

    float acc0[2][8], acc1[2][8];
#pragma unroll
    for (int r = 0; r < 2; ++r)
#pragma unroll
        for (int j = 0; j < 8; ++j) { acc0[r][j] = b0; acc1[r][j] = b1; }

    const float* xb = x + (size_t)b * 3 * HW;
#pragma unroll
    for (int ci = 0; ci < 3; ++ci) {
        const float* xc = xb + ci * HW;
#pragma unroll
        for (int iy = 0; iy < 4; ++iy) {        // input rows y0-1 .. y0+2
            int yy = y0 - 1 + iy;
            if (yy < 0 || yy >= HH) continue;   // uniform
            const float* r = xc + yy * WW;
            float4 cA = *(const float4*)(r + xs);
            float4 cB = *(const float4*)(r + xs + 4);
            float l  = (xs > 0)      ? r[xs - 1] : 0.f;
            float rr = (xs < WW - 8) ? r[xs + 8] : 0.f;
            float v[10] = {l, cA.x, cA.y, cA.z, cA.w,
                           cB.x, cB.y, cB.z, cB.w, rr};
#pragma unroll
            for (int orow = 0; orow < 2; ++orow) {
                int kh = iy - orow;
                if (kh < 0 || kh > 2) continue;  // compile-time
                float w00 = W[ci * 9 + kh * 3 + 0];
                float w01 = W[ci * 9 + kh * 3 + 1];
                float w02 = W[ci * 9 + kh * 3 + 2];
                float w10 = W[27 + ci * 9 + kh * 3 + 0];
                float w11 = W[27 + ci * 9 + kh * 3 + 1];
                float w12 = W[27 + ci * 9 + kh * 3 + 2];
#pragma unroll
                for (int j = 0; j < 8; ++j) {
                    acc0[orow][j] = fmaf(w00, v[j],
                                    fmaf(w01, v[j + 1],
                                    fmaf(w02, v[j + 2], acc0[orow][j])));
                    acc1[orow][j] = fmaf(w10, v[j],
                                    fmaf(w11, v[j + 1],
                                    fmaf(w12, v[j + 2], acc1[orow][j])));
                }
            }
        }
    }
#pragma unroll
    for (int orow = 0; orow < 2; ++orow) {
        size_t o = (size_t)b * HW + (size_t)(y0 + orow) * WW + xs;
        half8v h0, h1;
#pragma unroll
        for (int j = 0; j < 8; ++j) {
            h0[j] = (half_t)acc0[orow][j];
            h1[j] = (half_t)(acc1[orow][j] - acc0[orow][j]);
        }
        *(half8v*)(u0p + o) = h0;
        *(half8v*)(dup + o) = h1;
    }
}

// ---------------------------------------------------------------------------
// Kernel 2: two fused CRF iterations (trapezoid), fp16 planes, NO min-waves
// launch bound (VGPR free -> no spill; ~90 live floats in regs).
//   stage A: mid = du + 2*blur(sig(src)) - S  for 18 intermediate rows (regs)
//   stage B: d'  = du + 2*blur(sig(mid)) - S  for 8 own rows -> fp16
// Reads src slab rows y0-10..y0+17 (L2-resident), du rows y0-5..y0+12.
// ---------------------------------------------------------------------------
__global__ __launch_bounds__(256) void crf_pair(
    const half_t* __restrict__ sp, const half_t* __restrict__ dup,
    half_t* __restrict__ dnxt)
{
    __shared__ float v[18][528];

    int bid  = blockIdx.x;
    int tile = (bid & 7) * 128 + (bid >> 3);   // grid 1024, bijective
    int b    = tile >> 6;
    int y0   = (tile & 63) << 3;
    int tid  = threadIdx.x;
    int x0   = tid << 1;

    if (tid < 5) {
#pragma unroll
        for (int r = 0; r < 18; ++r) { v[r][tid] = 0.f; v[r][517 + tid] = 0.f; }
    }

    size_t pb = (size_t)b * HW + x0;
    float SxA = edgeS(x0), SxB = edgeS(x0 + 1);

    // ---- stage A: vblur(sig(src)) for 18 intermediate rows ----
    float st[18][2] = {{0.f}};
#pragma unroll
    for (int i = 0; i < 28; ++i) {             // src rows y0-10 .. y0+17
        int yy = y0 + i - 10;
        if (yy < 0 || yy >= HH) continue;      // uniform
        half2v dv = *(const half2v*)(sp + pb + (size_t)yy * WW);
        float qa = sig1((float)dv[0]), qb = sig1((float)dv[1]);
#pragma unroll
        for (int r1 = 0; r1 < 18; ++r1) {
            int dt = i - r1;
            if (dt < 0 || dt > 10) continue;   // compile-time
            float k = GK[dt];
            st[r1][0] = fmaf(k, qa, st[r1][0]);
            st[r1][1] = fmaf(k, qb, st[r1][1]);
        }
    }
#pragma unroll
    for (int r1 = 0; r1 < 18; ++r1)
        *(float2*)(&v[r1][5 + x0]) = make_float2(st[r1][0], st[r1][1]);
    __syncthreads();

    // ---- stage A hblur + mid update (regs); capture du for own rows ----
    float duo[8][2];
#pragma unroll
    for (int r1 = 0; r1 < 18; ++r1) {
        int yy = y0 + r1 - 5;
        if (yy < 0 || yy >= HH) continue;      // uniform
        float wv[12];
#pragma unroll
        for (int t = 0; t < 6; ++t)
            *(float2*)&wv[2 * t] = *(const float2*)(&v[r1][x0 + 2 * t]);
        float m0 = 0.f, m1 = 0.f;
#pragma unroll
        for (int t = 0; t < 11; ++t) {
            m0 = fmaf(GK[t], wv[t], m0);
            m1 = fmaf(GK[t], wv[t + 1], m1);
        }
        half2v duv = *(const half2v*)(dup + pb + (size_t)yy * WW);
        float dua = (float)duv[0], dub = (float)duv[1];
        if (r1 >= 5 && r1 < 13) {
            duo[r1 - 5][0] = dua;
            duo[r1 - 5][1] = dub;
        }
        float Sy = edgeS(yy);
        st[r1][0] = dua + fmaf(2.f, m0, -(SxA * Sy));
        st[r1][1] = dub + fmaf(2.f, m1, -(SxB * Sy));
    }

    // ---- stage B: vblur(sig(mid)) for 8 own rows ----
    float acc[8][2] = {{0.f}};
#pragma unroll
    for (int r1 = 0; r1 < 18; ++r1) {
        int yy = y0 + r1 - 5;
        if (yy < 0 || yy >= HH) continue;      // uniform
        float qa = sig1(st[r1][0]), qb = sig1(st[r1][1]);
#pragma unroll
        for (int r = 0; r < 8; ++r) {
            int dt = r1 - r;
            if (dt < 0 || dt > 10) continue;   // compile-time
            float k = GK[dt];
            acc[r][0] = fmaf(k, qa, acc[r][0]);
            acc[r][1] = fmaf(k, qb, acc[r][1]);
        }
    }
    __syncthreads();                           // stage-A v reads all done
#pragma unroll
    for (int r = 0; r < 8; ++r)
        *(float2*)(&v[r][5 + x0]) = make_float2(acc[r][0], acc[r][1]);
    __syncthreads();

#pragma unroll
    for (int r = 0; r < 8; ++r) {
        int yy = y0 + r;
        float Sy = edgeS(yy);
        float wv[12];
#pragma unroll
        for (int t = 0; t < 6; ++t)
            *(float2*)&wv[2 * t] = *(const float2*)(&v[r][x0 + 2 * t]);
        float m0 = 0.f, m1 = 0.f;
#pragma unroll
        for (int t = 0; t < 11; ++t) {
            m0 = fmaf(GK[t], wv[t], m0);
            m1 = fmaf(GK[t], wv[t + 1], m1);
        }
        half2v hw;
        hw[0] = (half_t)(duo[r][0] + fmaf(2.f, m0, -(SxA * Sy)));
        hw[1] = (half_t)(duo[r][1] + fmaf(2.f, m1, -(SxB * Sy)));
        *(half2v*)(dnxt + pb + (size_t)yy * WW) = hw;
    }
}

// ---------------------------------------------------------------------------
// Kernel 3: final single CRF iteration + epilogue (round-11 MODE 2 proven).
//   m = blur(sigmoid(d4)); out0 = u0 + S - m ; out1 = u0 + du + m (fp32)
// ---------------------------------------------------------------------------
__global__ __launch_bounds__(256) void crf_final(
    const half_t* __restrict__ dcur, const half_t* __restrict__ dup,
    const half_t* __restrict__ u0p, float* __restrict__ outp)
{
    __shared__ float v[8][528];

    int bid  = blockIdx.x;
    int tile = (bid & 7) * 128 + (bid >> 3);   // grid 1024, bijective
    int b    = tile >> 6;
    int y0   = (tile & 63) << 3;
    int tid  = threadIdx.x;
    int x0   = tid << 1;

    if (tid < 5) {
#pragma unroll
        for (int r = 0; r < 8; ++r) {
            v[r][tid] = 0.f;
            v[r][517 + tid] = 0.f;
        }
    }

    size_t pb = (size_t)b * HW + x0;

    float acc[8][2] = {{0.f}};
#pragma unroll
    for (int i = 0; i < 18; ++i) {             // input rows y0-5 .. y0+12
        int yy = y0 + i - 5;
        if (yy < 0 || yy >= HH) continue;      // uniform
        half2v dv = *(const half2v*)(dcur + pb + (size_t)yy * WW);
        float qa = sig1((float)dv[0]), qb = sig1((float)dv[1]);
#pragma unroll
        for (int r = 0; r < 8; ++r) {
            int dt = i - r;
            if (dt < 0 || dt > 10) continue;   // compile-time
            float k = GK[dt];
            acc[r][0] = fmaf(k, qa, acc[r][0]);
            acc[r][1] = fmaf(k, qb, acc[r][1]);
        }
    }
#pragma unroll
    for (int r = 0; r < 8; ++r)
        *(float2*)(&v[r][5 + x0]) = make_float2(acc[r][0], acc[r][1]);
    __syncthreads();

    float SxA = edgeS(x0), SxB = edgeS(x0 + 1);

#pragma unroll
    for (int r = 0; r < 8; ++r) {
        int yy = y0 + r;
        float Sy = edgeS(yy);

        float wv[12];
#pragma unroll
        for (int t = 0; t < 6; ++t)
            *(float2*)&wv[2 * t] = *(const float2*)(&v[r][x0 + 2 * t]);

        float m0 = 0.f, m1 = 0.f;
#pragma unroll
        for (int t = 0; t < 11; ++t) {
            m0 = fmaf(GK[t], wv[t], m0);
            m1 = fmaf(GK[t], wv[t + 1], m1);
        }

        size_t po = pb + (size_t)yy * WW;
        half2v duv = *(const half2v*)(dup + po);
        half2v u0v = *(const half2v*)(u0p + po);
        float dua = (float)duv[0], dub = (float)duv[1];
        float ua  = (float)u0v[0], ub  = (float)u0v[1];

        float S0 = SxA * Sy, S1 = SxB * Sy;
        size_t oo = (size_t)b * 2 * HW + (size_t)yy * WW + x0;
        *(float2*)(outp + oo)      = make_float2(ua + (S0 - m0),
                                                 ub + (S1 - m1));
        *(float2*)(outp + oo + HW) = make_float2((ua + dua) + m0,
                                                 (ub + dub) + m1);
    }
}

extern "C" void kernel_launch(void* const* d_in, const int* in_sizes, int n_in,
                              void* d_out, int out_size, void* d_ws, size_t ws_size,
                              hipStream_t stream) {
    const float* x    = (const float*)d_in[0];   // (16,3,512,512)
    const float* w    = (const float*)d_in[1];   // (2,3,3,3)
    const float* bias = (const float*)d_in[2];   // (2,)

    float*  out = (float*)d_out;                 // (16,2,512,512) fp32
    half_t* u0p = (half_t*)d_ws;                 // 8.4 MB
    half_t* dup = u0p + NP1;                     // 8.4 MB
    half_t* dA  = dup + NP1;                     // 8.4 MB
    half_t* dB  = dA + NP1;                      // 8.4 MB

    conv3x3_du<<<1024, 256, 0, stream>>>(x, w, bias, u0p, dup);
    crf_pair<<<1024, 256, 0, stream>>>(dup, dup, dA);        // it0+it1 -> d2
    crf_pair<<<1024, 256, 0, stream>>>(dA,  dup, dB);        // it2+it3 -> d4
    crf_final<<<1024, 256, 0, stream>>>(dB, dup, u0p, out);  // it4 -> out
}

// Round 13
// 69.414 us; speedup vs baseline: 1.2960x; 1.2960x over previous
//
#include <hip/hip_runtime.h>

constexpr int BB = 16;        // batch
constexpr int HH = 512;
constexpr int WW = 512;
constexpr int HW = HH * WW;   // 262144 = 2^18
constexpr int NP1 = BB * HW;  // one single-channel plane (elements)

using half_t = _Float16;
using half2v = __attribute__((ext_vector_type(2))) _Float16;
using half8v = __attribute__((ext_vector_type(8))) _Float16;

#if __has_builtin(__builtin_elementwise_fma)
#define HFMA2(a, b, c) __builtin_elementwise_fma((a), (b), (c))
#else
#define HFMA2(a, b, c) ((a) * (b) + (c))
#endif

// 11-tap Gaussian, theta=1, normalized (== normal pdf values to ~1e-8 rel).
__device__ constexpr float GK[11] = {
    1.4867195147342977e-06f,
    1.3383022576488537e-04f,
    4.4318484119380075e-03f,
    5.3990966513188063e-02f,
    2.4197072451914337e-01f,
    3.9894228040143270e-01f,
    2.4197072451914337e-01f,
    5.3990966513188063e-02f,
    4.4318484119380075e-03f,
    1.3383022576488537e-04f,
    1.4867195147342977e-06f,
};
// prefix sums of the smallest taps: PFX[k] = GK[0]+..+GK[k-1]
__device__ constexpr float PFX[6] = {
    0.0f,
    1.4867195147342977e-06f,
    1.3531694527962e-04f,
    4.5671653572176e-03f,
    5.8558131870406e-02f,
    3.0052885638955e-01f,
};

// blur(ones) separable factor with zero padding
__device__ __forceinline__ float edgeS(int i) {
    float s = 1.f;
    if (i < 5)   s -= PFX[5 - i];
    if (i > 506) s -= PFX[i - 506];
    return s;
}

__device__ __forceinline__ float sig1(float d) {
    d = fminf(fmaxf(d, -30.f), 30.f);
    float e = __expf(d);
    return e * __builtin_amdgcn_rcpf(1.f + e);
}

// ---------------------------------------------------------------------------
// Kernel 1: 3x3 conv, C_in=3 -> C_out=2, SAME zero-pad (round-11 proven).
// 2 output rows x 8 px per thread. Writes fp16 u0, du, and q0 = sigmoid(du).
// ---------------------------------------------------------------------------
__global__ __launch_bounds__(256) void conv3x3_duq(
    const float* __restrict__ x, const float* __restrict__ w,
    const float* __restrict__ bias, half_t* __restrict__ u0p,
    half_t* __restrict__ dup, half_t* __restrict__ q0p)
{
    int bid = blockIdx.x;
    int sb  = (bid & 7) * 128 + (bid >> 3);     // grid 1024, bijective
    int t   = sb * 256 + threadIdx.x;
    int b   = t >> 14;                          // 16384 threads / image
    int rem = t & 16383;
    int y0  = (rem >> 6) << 1;                  // row pair 0,2,..,510
    int xs  = (rem & 63) << 3;                  // 8-px strip

    float W[54];
#pragma unroll
    for (int i = 0; i < 13; ++i)
        *(float4*)&W[4 * i] = *(const float4*)(w + 4 * i);
    W[52] = w[52];
    W[53] = w[53];
    float b0 = bias[0], b1 = bias[1];

    float acc0[2][8], acc1[2][8];
#pragma unroll
    for (int r = 0; r < 2; ++r)
#pragma unroll
        for (int j = 0; j < 8; ++j) { acc0[r][j] = b0; acc1[r][j] = b1; }

    const float* xb = x + (size_t)b * 3 * HW;
#pragma unroll
    for (int ci = 0; ci < 3; ++ci) {
        const float* xc = xb + ci * HW;
#pragma unroll
        for (int iy = 0; iy < 4; ++iy) {        // input rows y0-1 .. y0+2
            int yy = y0 - 1 + iy;
            if (yy < 0 || yy >= HH) continue;   // uniform
            const float* r = xc + yy * WW;
            float4 cA = *(const float4*)(r + xs);
            float4 cB = *(const float4*)(r + xs + 4);
            float l  = (xs > 0)      ? r[xs - 1] : 0.f;
            float rr = (xs < WW - 8) ? r[xs + 8] : 0.f;
            float v[10] = {l, cA.x, cA.y, cA.z, cA.w,
                           cB.x, cB.y, cB.z, cB.w, rr};
#pragma unroll
            for (int orow = 0; orow < 2; ++orow) {
                int kh = iy - orow;
                if (kh < 0 || kh > 2) continue;  // compile-time
                float w00 = W[ci * 9 + kh * 3 + 0];
                float w01 = W[ci * 9 + kh * 3 + 1];
                float w02 = W[ci * 9 + kh * 3 + 2];
                float w10 = W[27 + ci * 9 + kh * 3 + 0];
                float w11 = W[27 + ci * 9 + kh * 3 + 1];
                float w12 = W[27 + ci * 9 + kh * 3 + 2];
#pragma unroll
                for (int j = 0; j < 8; ++j) {
                    acc0[orow][j] = fmaf(w00, v[j],
                                    fmaf(w01, v[j + 1],
                                    fmaf(w02, v[j + 2], acc0[orow][j])));
                    acc1[orow][j] = fmaf(w10, v[j],
                                    fmaf(w11, v[j + 1],
                                    fmaf(w12, v[j + 2], acc1[orow][j])));
                }
            }
        }
    }
#pragma unroll
    for (int orow = 0; orow < 2; ++orow) {
        size_t o = (size_t)b * HW + (size_t)(y0 + orow) * WW + xs;
        half8v h0, h1, hq;
#pragma unroll
        for (int j = 0; j < 8; ++j) {
            float du = acc1[orow][j] - acc0[orow][j];
            h0[j] = (half_t)acc0[orow][j];
            h1[j] = (half_t)du;
            hq[j] = (half_t)sig1(du);
        }
        *(half8v*)(u0p + o) = h0;
        *(half8v*)(dup + o) = h1;
        *(half8v*)(q0p + o) = hq;
    }
}

// ---------------------------------------------------------------------------
// Kernel 2: one CRF iteration in q-space.
//   m = blur(q);  d' = du + 2*m - Sx*Sy;  q' = sigmoid(d')
// vblur is PACKED fp16: the half2 load is the (x0,x0+1) pair -> one pk_fma
// per input row per thread (88 total). No sigmoid on halo reads.
// 8 output rows per block; 256 threads x 2 px; grid 1024 (XCD-bijective).
// ---------------------------------------------------------------------------
__global__ __launch_bounds__(256) void q_iter(
    const half_t* __restrict__ qp, const half_t* __restrict__ dup,
    half_t* __restrict__ qnxt)
{
    __shared__ float v[8][528];

    int bid  = blockIdx.x;
    int tile = (bid & 7) * 128 + (bid >> 3);   // grid 1024, bijective
    int b    = tile >> 6;                      // 64 tiles / image
    int y0   = (tile & 63) << 3;               // 8 output rows
    int tid  = threadIdx.x;
    int x0   = tid << 1;                       // 2 px per thread

    if (tid < 5) {
#pragma unroll
        for (int r = 0; r < 8; ++r) {
            v[r][tid] = 0.f;
            v[r][517 + tid] = 0.f;
        }
    }

    size_t pb = (size_t)b * HW + x0;

    half2v acc[8];
#pragma unroll
    for (int r = 0; r < 8; ++r) acc[r] = half2v{(half_t)0.f, (half_t)0.f};

#pragma unroll
    for (int i = 0; i < 18; ++i) {             // input rows y0-5 .. y0+12
        int yy = y0 + i - 5;
        if (yy < 0 || yy >= HH) continue;      // uniform
        half2v qv = *(const half2v*)(qp + pb + (size_t)yy * WW);
#pragma unroll
        for (int r = 0; r < 8; ++r) {
            int dt = i - r;
            if (dt < 0 || dt > 10) continue;   // compile-time
            half_t kh = (half_t)GK[dt];
            half2v kv = half2v{kh, kh};
            acc[r] = HFMA2(kv, qv, acc[r]);
        }
    }
#pragma unroll
    for (int r = 0; r < 8; ++r)
        *(float2*)(&v[r][5 + x0]) =
            make_float2((float)acc[r][0], (float)acc[r][1]);
    __syncthreads();

    float SxA = edgeS(x0), SxB = edgeS(x0 + 1);

#pragma unroll
    for (int r = 0; r < 8; ++r) {
        int yy = y0 + r;
        float Sy = edgeS(yy);

        float wv[12];
#pragma unroll
        for (int t = 0; t < 6; ++t)
            *(float2*)&wv[2 * t] = *(const float2*)(&v[r][x0 + 2 * t]);

        float m0 = 0.f, m1 = 0.f;
#pragma unroll
        for (int t = 0; t < 11; ++t) {
            m0 = fmaf(GK[t], wv[t], m0);
            m1 = fmaf(GK[t], wv[t + 1], m1);
        }

        size_t po = pb + (size_t)yy * WW;
        half2v duv = *(const half2v*)(dup + po);
        float d0 = (float)duv[0] + fmaf(2.f, m0, -(SxA * Sy));
        float d1 = (float)duv[1] + fmaf(2.f, m1, -(SxB * Sy));

        half2v hq;
        hq[0] = (half_t)sig1(d0);
        hq[1] = (half_t)sig1(d1);
        *(half2v*)(qnxt + po) = hq;
    }
}

// ---------------------------------------------------------------------------
// Kernel 3: final blur of q4 + epilogue (fp32 NCHW out).
//   m = blur(q4); out0 = u0 + S - m ; out1 = u0 + du + m
// ---------------------------------------------------------------------------
__global__ __launch_bounds__(256) void q_final(
    const half_t* __restrict__ qp, const half_t* __restrict__ dup,
    const half_t* __restrict__ u0p, float* __restrict__ outp)
{
    __shared__ float v[8][528];

    int bid  = blockIdx.x;
    int tile = (bid & 7) * 128 + (bid >> 3);   // grid 1024, bijective
    int b    = tile >> 6;
    int y0   = (tile & 63) << 3;
    int tid  = threadIdx.x;
    int x0   = tid << 1;

    if (tid < 5) {
#pragma unroll
        for (int r = 0; r < 8; ++r) {
            v[r][tid] = 0.f;
            v[r][517 + tid] = 0.f;
        }
    }

    size_t pb = (size_t)b * HW + x0;

    half2v acc[8];
#pragma unroll
    for (int r = 0; r < 8; ++r) acc[r] = half2v{(half_t)0.f, (half_t)0.f};

#pragma unroll
    for (int i = 0; i < 18; ++i) {             // input rows y0-5 .. y0+12
        int yy = y0 + i - 5;
        if (yy < 0 || yy >= HH) continue;      // uniform
        half2v qv = *(const half2v*)(qp + pb + (size_t)yy * WW);
#pragma unroll
        for (int r = 0; r < 8; ++r) {
            int dt = i - r;
            if (dt < 0 || dt > 10) continue;   // compile-time
            half_t kh = (half_t)GK[dt];
            half2v kv = half2v{kh, kh};
            acc[r] = HFMA2(kv, qv, acc[r]);
        }
    }
#pragma unroll
    for (int r = 0; r < 8; ++r)
        *(float2*)(&v[r][5 + x0]) =
            make_float2((float)acc[r][0], (float)acc[r][1]);
    __syncthreads();

    float SxA = edgeS(x0), SxB = edgeS(x0 + 1);

#pragma unroll
    for (int r = 0; r < 8; ++r) {
        int yy = y0 + r;
        float Sy = edgeS(yy);

        float wv[12];
#pragma unroll
        for (int t = 0; t < 6; ++t)
            *(float2*)&wv[2 * t] = *(const float2*)(&v[r][x0 + 2 * t]);

        float m0 = 0.f, m1 = 0.f;
#pragma unroll
        for (int t = 0; t < 11; ++t) {
            m0 = fmaf(GK[t], wv[t], m0);
            m1 = fmaf(GK[t], wv[t + 1], m1);
        }

        size_t po = pb + (size_t)yy * WW;
        half2v duv = *(const half2v*)(dup + po);
        half2v u0v = *(const half2v*)(u0p + po);
        float dua = (float)duv[0], dub = (float)duv[1];
        float ua  = (float)u0v[0], ub  = (float)u0v[1];

        float S0 = SxA * Sy, S1 = SxB * Sy;
        size_t oo = (size_t)b * 2 * HW + (size_t)yy * WW + x0;
        *(float2*)(outp + oo)      = make_float2(ua + (S0 - m0),
                                                 ub + (S1 - m1));
        *(float2*)(outp + oo + HW) = make_float2((ua + dua) + m0,
                                                 (ub + dub) + m1);
    }
}

extern "C" void kernel_launch(void* const* d_in, const int* in_sizes, int n_in,
                              void* d_out, int out_size, void* d_ws, size_t ws_size,
                              hipStream_t stream) {
    const float* x    = (const float*)d_in[0];   // (16,3,512,512)
    const float* w    = (const float*)d_in[1];   // (2,3,3,3)
    const float* bias = (const float*)d_in[2];   // (2,)

    float*  out = (float*)d_out;                 // (16,2,512,512) fp32
    half_t* u0p = (half_t*)d_ws;                 // 8.4 MB
    half_t* dup = u0p + NP1;                     // 8.4 MB
    half_t* qA  = dup + NP1;                     // 8.4 MB
    half_t* qB  = qA + NP1;                      // 8.4 MB

    conv3x3_duq<<<1024, 256, 0, stream>>>(x, w, bias, u0p, dup, qA);  // q0
    q_iter<<<1024, 256, 0, stream>>>(qA, dup, qB);                    // q1
    q_iter<<<1024, 256, 0, stream>>>(qB, dup, qA);                    // q2
    q_iter<<<1024, 256, 0, stream>>>(qA, dup, qB);                    // q3
    q_iter<<<1024, 256, 0, stream>>>(qB, dup, qA);                    // q4
    q_final<<<1024, 256, 0, stream>>>(qA, dup, u0p, out);             // out
}